// Round 1
// baseline (402.526 us; speedup 1.0000x reference)
//
#include <hip/hip_runtime.h>
#include <hip/hip_bf16.h>
#include <math.h>

#define N 8192
#define D 128
#define MARGIN 0.3f

#define TI 128          // i-rows per block
#define TJ 128          // j-rows per tile
#define JCH 8           // j chunks (gridDim.y)
#define JT_PER (N / (TJ * JCH))   // j-tiles per block = 8

// ---------------- row squared-norms ----------------
__global__ __launch_bounds__(256) void sq_kernel(const float* __restrict__ X,
                                                 float* __restrict__ sq) {
    int tid = threadIdx.x;
    int row = blockIdx.x * 16 + (tid >> 4);
    int l = tid & 15;
    const float4* p = reinterpret_cast<const float4*>(X + (size_t)row * D + l * 8);
    float4 u = p[0];
    float4 v = p[1];
    float s = u.x*u.x + u.y*u.y + u.z*u.z + u.w*u.w
            + v.x*v.x + v.y*v.y + v.z*v.z + v.w*v.w;
    #pragma unroll
    for (int off = 8; off >= 1; off >>= 1) s += __shfl_xor(s, off);
    if (l == 0) sq[row] = s;
}

// ---------------- main: Gram tile + masked max/min mining ----------------
// LDS layout: XOR-swizzled float4 chunks, chunk c of row stored at (c ^ (row&7)).
// A tile: [128 rows][64 k] (one k-half), B tile: [128 rows][32 k] (one k-quarter).
__global__ __launch_bounds__(256) void triplet_main(const float* __restrict__ X,
                                                    const int* __restrict__ lbl,
                                                    const float* __restrict__ sq,
                                                    unsigned* __restrict__ ap2,
                                                    unsigned* __restrict__ an2) {
    __shared__ float As[TI * 64];
    __shared__ float Bs[TJ * 32];
    __shared__ float sqj_s[TJ];
    __shared__ int   lblj_s[TJ];

    const int tid = threadIdx.x;
    const int tx = tid & 15;          // j-stripe lane
    const int ty = tid >> 4;          // i-stripe lane
    const int i0 = blockIdx.x * TI;

    int lbl_i[8];
    #pragma unroll
    for (int r = 0; r < 8; ++r) lbl_i[r] = lbl[i0 + ty + 16 * r];

    float m_ap[8], m_an[8];
    #pragma unroll
    for (int r = 0; r < 8; ++r) { m_ap[r] = -INFINITY; m_an[r] = INFINITY; }

    for (int jt = 0; jt < JT_PER; ++jt) {
        const int jb = (blockIdx.y * JT_PER + jt) * TJ;
        __syncthreads();              // previous tile's readers done
        if (tid < TJ) { sqj_s[tid] = sq[jb + tid]; lblj_s[tid] = lbl[jb + tid]; }

        float acc[8][8];
        #pragma unroll
        for (int r = 0; r < 8; ++r)
            #pragma unroll
            for (int s = 0; s < 8; ++s) acc[r][s] = 0.f;

        #pragma unroll
        for (int phase = 0; phase < 4; ++phase) {
            const int aphase = phase >> 1;
            const int bphase = phase & 1;
            if (phase > 0) __syncthreads();   // prior compute done before overwrite
            if (bphase == 0) {
                // stage A half: rows i0..+127, k = aphase*64..+63 (16 chunks/row)
                #pragma unroll
                for (int it = 0; it < 8; ++it) {
                    int cl = tid + it * 256;
                    int row = cl >> 4, c = cl & 15;
                    float4 v = *reinterpret_cast<const float4*>(
                        X + (size_t)(i0 + row) * D + aphase * 64 + c * 4);
                    *reinterpret_cast<float4*>(
                        &As[row * 64 + ((c ^ (row & 7)) << 2)]) = v;
                }
            }
            // stage B quarter: rows jb..+127, k = aphase*64 + bphase*32 (8 chunks/row)
            #pragma unroll
            for (int it = 0; it < 4; ++it) {
                int cl = tid + it * 256;
                int row = cl >> 3, c = cl & 7;
                float4 v = *reinterpret_cast<const float4*>(
                    X + (size_t)(jb + row) * D + aphase * 64 + bphase * 32 + c * 4);
                *reinterpret_cast<float4*>(
                    &Bs[row * 32 + ((c ^ (row & 7)) << 2)]) = v;
            }
            __syncthreads();                  // staging visible

            #pragma unroll
            for (int c8 = 0; c8 < 8; ++c8) {
                const int ca = (bphase * 8 + c8) ^ (ty & 7);   // row_i&7 == ty&7
                const int cb = c8 ^ (tx & 7);                  // row_j&7 == tx&7
                float4 b[8];
                #pragma unroll
                for (int s = 0; s < 8; ++s)
                    b[s] = *reinterpret_cast<const float4*>(
                        &Bs[(tx + 16 * s) * 32 + (cb << 2)]);
                #pragma unroll
                for (int r = 0; r < 8; ++r) {
                    float4 a = *reinterpret_cast<const float4*>(
                        &As[(ty + 16 * r) * 64 + (ca << 2)]);
                    #pragma unroll
                    for (int s = 0; s < 8; ++s) {
                        acc[r][s] += a.x * b[s].x;
                        acc[r][s] += a.y * b[s].y;
                        acc[r][s] += a.z * b[s].z;
                        acc[r][s] += a.w * b[s].w;
                    }
                }
            }
        }

        // epilogue: masked running max/min on v = sq_j - 2*dot  (monotone in d2)
        #pragma unroll
        for (int s = 0; s < 8; ++s) {
            int lj = lblj_s[tx + 16 * s];
            float sj = sqj_s[tx + 16 * s];
            #pragma unroll
            for (int r = 0; r < 8; ++r) {
                float v = sj - 2.f * acc[r][s];
                bool same = (lj == lbl_i[r]);
                m_ap[r] = same ? fmaxf(m_ap[r], v) : m_ap[r];
                m_an[r] = same ? m_an[r] : fminf(m_an[r], v);
            }
        }
    }

    // reduce across the 16 j-stripe lanes (contiguous within a wave)
    #pragma unroll
    for (int off = 8; off >= 1; off >>= 1) {
        #pragma unroll
        for (int r = 0; r < 8; ++r) {
            m_ap[r] = fmaxf(m_ap[r], __shfl_xor(m_ap[r], off));
            m_an[r] = fminf(m_an[r], __shfl_xor(m_an[r], off));
        }
    }
    if (tx == 0) {
        #pragma unroll
        for (int r = 0; r < 8; ++r) {
            int row = i0 + ty + 16 * r;
            float si = sq[row];
            float vap = fmaxf(si + m_ap[r], 1e-12f);  // clip -> positive
            float van = fmaxf(si + m_an[r], 1e-12f);
            // positive floats order like uints
            atomicMax(&ap2[row], __float_as_uint(vap));
            atomicMin(&an2[row], __float_as_uint(van));
        }
    }
}

// ---------------- finalize: sqrt + hinge + mean ----------------
__global__ __launch_bounds__(256) void finalize_kernel(const unsigned* __restrict__ ap2,
                                                       const unsigned* __restrict__ an2,
                                                       float* __restrict__ out) {
    int tid = threadIdx.x;
    float ls = 0.f, ps = 0.f;
    for (int row = tid; row < N; row += 256) {
        float ap = sqrtf(__uint_as_float(ap2[row]));
        float an = sqrtf(__uint_as_float(an2[row]));
        ls += fmaxf(0.f, MARGIN - (an - ap));
        ps += (an > ap) ? 1.f : 0.f;
    }
    #pragma unroll
    for (int off = 32; off >= 1; off >>= 1) {
        ls += __shfl_xor(ls, off);
        ps += __shfl_xor(ps, off);
    }
    __shared__ float red[2][4];
    int w = tid >> 6;
    if ((tid & 63) == 0) { red[0][w] = ls; red[1][w] = ps; }
    __syncthreads();
    if (tid == 0) {
        float L = red[0][0] + red[0][1] + red[0][2] + red[0][3];
        float P = red[1][0] + red[1][1] + red[1][2] + red[1][3];
        out[0] = L / (float)N;
        out[1] = P / (float)N;
    }
}

extern "C" void kernel_launch(void* const* d_in, const int* in_sizes, int n_in,
                              void* d_out, int out_size, void* d_ws, size_t ws_size,
                              hipStream_t stream) {
    const float* X = (const float*)d_in[0];
    const int* lbl = (const int*)d_in[1];
    float* out = (float*)d_out;

    float* sq = (float*)d_ws;                      // N floats
    unsigned* ap2 = (unsigned*)d_ws + N;           // N uints (float bits)
    unsigned* an2 = (unsigned*)d_ws + 2 * N;       // N uints

    // ws is re-poisoned to 0xAA before every launch: init mining arrays.
    hipMemsetAsync(ap2, 0x00, N * sizeof(unsigned), stream);   // 0.0f  (< any clipped d2)
    hipMemsetAsync(an2, 0x7F, N * sizeof(unsigned), stream);   // 3.39e38 (> any d2)

    sq_kernel<<<N / 16, 256, 0, stream>>>(X, sq);
    dim3 grid(N / TI, JCH);
    triplet_main<<<grid, 256, 0, stream>>>(X, lbl, sq, ap2, an2);
    finalize_kernel<<<1, 256, 0, stream>>>(ap2, an2, out);
}

// Round 2
// 106.943 us; speedup vs baseline: 3.7639x; 3.7639x over previous
//
#include <hip/hip_runtime.h>
#include <hip/hip_bf16.h>
#include <math.h>

#define N 8192
#define D 128
#define MARGIN 0.3f

#define TI 128
#define TJ 128
#define JCH 8
#define JT_PER (N / (TJ * JCH))   // 8 j-tiles per block

typedef float f32x4 __attribute__((ext_vector_type(4)));
typedef short bf16x8 __attribute__((ext_vector_type(8)));
typedef unsigned short u16x8 __attribute__((ext_vector_type(8)));

#define AS1 __attribute__((address_space(1)))
#define AS3 __attribute__((address_space(3)))

__device__ inline void gload_lds16(const void* g, void* l) {
    __builtin_amdgcn_global_load_lds((AS1 void*)(void*)(g), (AS3 void*)(l), 16, 0, 0);
}

__device__ inline unsigned short f2bf(float f) {
    unsigned u = __float_as_uint(f);
    unsigned r = (u + 0x7FFFu + ((u >> 16) & 1u)) >> 16;
    return (unsigned short)r;
}

// ---------- convert fp32 -> bf16 + row squared-norms (fp32, exact) ----------
__global__ __launch_bounds__(256) void convert_kernel(const float* __restrict__ X,
                                                      unsigned short* __restrict__ Xb,
                                                      float* __restrict__ sq) {
    int tid = threadIdx.x;
    int row = blockIdx.x * 16 + (tid >> 4);
    int l = tid & 15;
    const float4* p = reinterpret_cast<const float4*>(X + (size_t)row * D + l * 8);
    float4 u = p[0];
    float4 v = p[1];
    float s = u.x*u.x + u.y*u.y + u.z*u.z + u.w*u.w
            + v.x*v.x + v.y*v.y + v.z*v.z + v.w*v.w;
    u16x8 o;
    o[0] = f2bf(u.x); o[1] = f2bf(u.y); o[2] = f2bf(u.z); o[3] = f2bf(u.w);
    o[4] = f2bf(v.x); o[5] = f2bf(v.y); o[6] = f2bf(v.z); o[7] = f2bf(v.w);
    *reinterpret_cast<u16x8*>(Xb + (size_t)row * D + l * 8) = o;
    #pragma unroll
    for (int off = 8; off >= 1; off >>= 1) s += __shfl_xor(s, off);
    if (l == 0) sq[row] = s;
}

// ---------- main: bf16 MFMA Gram tile + masked max/min mining ----------
// LDS tiles row-major, 16 chunks of 16B per row; chunk swizzle: LDS chunk c of
// row r holds GLOBAL chunk c ^ (r&7) (swizzle applied by permuting the global
// source per lane, since global_load_lds dest is fixed base+lane*16).
__global__ __launch_bounds__(256, 2) void triplet_main(
        const unsigned short* __restrict__ Xb,
        const int* __restrict__ lbl,
        const float* __restrict__ sq,
        unsigned* __restrict__ ap2,
        unsigned* __restrict__ an2) {
    __shared__ unsigned short As[TI * D];   // 32 KB
    __shared__ unsigned short Bs[TJ * D];   // 32 KB
    __shared__ float sqj_s[TJ];
    __shared__ int   lblj_s[TJ];

    const int tid = threadIdx.x;
    const int w = tid >> 6;        // wave 0..3
    const int lane = tid & 63;
    const int wr = w >> 1;         // wave row (2x2 wave grid over 128x128 C)
    const int wc = w & 1;          // wave col
    const int quad = lane >> 4;
    const int lx = lane & 15;
    const int i0 = blockIdx.x * TI;

    // labels of the 16 i-rows this lane owns (row = wr*64 + t_r*16 + quad*4 + v)
    int lbl_i[16];
    #pragma unroll
    for (int t = 0; t < 4; ++t)
        #pragma unroll
        for (int v = 0; v < 4; ++v)
            lbl_i[t * 4 + v] = lbl[i0 + wr * 64 + t * 16 + quad * 4 + v];

    float m_ap[16], m_an[16];
    #pragma unroll
    for (int q = 0; q < 16; ++q) { m_ap[q] = -INFINITY; m_an[q] = INFINITY; }

    // ---- stage A tile once (this block's 128 i-rows, full K=128) ----
    #pragma unroll
    for (int t = 0; t < 8; ++t) {
        int rbase = w * 32 + t * 4;
        int r = rbase + quad;
        int gc = lx ^ (r & 7);
        gload_lds16(Xb + (size_t)(i0 + r) * D + gc * 8, &As[rbase * D]);
    }

    #pragma unroll 1
    for (int jt = 0; jt < JT_PER; ++jt) {
        const int jb = (blockIdx.y * JT_PER + jt) * TJ;
        __syncthreads();   // prior tile's readers done; (iter 0: drains A staging)

        #pragma unroll
        for (int t = 0; t < 8; ++t) {
            int rbase = w * 32 + t * 4;
            int r = rbase + quad;
            int gc = lx ^ (r & 7);
            gload_lds16(Xb + (size_t)(jb + r) * D + gc * 8, &Bs[rbase * D]);
        }
        if (tid < TJ) { sqj_s[tid] = sq[jb + tid]; lblj_s[tid] = lbl[jb + tid]; }
        __syncthreads();   // staging visible

        f32x4 acc[4][4];
        #pragma unroll
        for (int a = 0; a < 4; ++a)
            #pragma unroll
            for (int b = 0; b < 4; ++b)
                acc[a][b] = (f32x4){0.f, 0.f, 0.f, 0.f};

        #pragma unroll
        for (int ks = 0; ks < 4; ++ks) {
            bf16x8 af[4], bf[4];
            #pragma unroll
            for (int t = 0; t < 4; ++t) {
                int rA = wr * 64 + t * 16 + lx;
                int sc = (ks * 4 + quad) ^ (rA & 7);
                af[t] = *reinterpret_cast<const bf16x8*>(&As[rA * D + sc * 8]);
            }
            #pragma unroll
            for (int t = 0; t < 4; ++t) {
                int rB = wc * 64 + t * 16 + lx;
                int sc = (ks * 4 + quad) ^ (rB & 7);
                bf[t] = *reinterpret_cast<const bf16x8*>(&Bs[rB * D + sc * 8]);
            }
            #pragma unroll
            for (int tr = 0; tr < 4; ++tr)
                #pragma unroll
                for (int tc = 0; tc < 4; ++tc)
                    acc[tr][tc] = __builtin_amdgcn_mfma_f32_16x16x32_bf16(
                        af[tr], bf[tc], acc[tr][tc], 0, 0, 0);
        }

        // ---- epilogue: masked running max/min on v = sq_j - 2*dot ----
        #pragma unroll
        for (int tc = 0; tc < 4; ++tc) {
            int cj = wc * 64 + tc * 16 + lx;
            int ljv = lblj_s[cj];
            float sjv = sqj_s[cj];
            #pragma unroll
            for (int tr = 0; tr < 4; ++tr) {
                #pragma unroll
                for (int v = 0; v < 4; ++v) {
                    float val = fmaf(-2.f, acc[tr][tc][v], sjv);
                    bool same = (ljv == lbl_i[tr * 4 + v]);
                    int q = tr * 4 + v;
                    m_ap[q] = same ? fmaxf(m_ap[q], val) : m_ap[q];
                    m_an[q] = same ? m_an[q] : fminf(m_an[q], val);
                }
            }
        }
    }

    // reduce each row over the 16 lanes of its quad (cols), then atomics
    #pragma unroll
    for (int off = 8; off >= 1; off >>= 1) {
        #pragma unroll
        for (int q = 0; q < 16; ++q) {
            m_ap[q] = fmaxf(m_ap[q], __shfl_xor(m_ap[q], off));
            m_an[q] = fminf(m_an[q], __shfl_xor(m_an[q], off));
        }
    }
    if (lx == 0) {
        #pragma unroll
        for (int t = 0; t < 4; ++t) {
            #pragma unroll
            for (int v = 0; v < 4; ++v) {
                int row = i0 + wr * 64 + t * 16 + quad * 4 + v;
                float si = sq[row];
                float vap = fmaxf(si + m_ap[t * 4 + v], 1e-12f);
                float van = fmaxf(si + m_an[t * 4 + v], 1e-12f);
                atomicMax(&ap2[row], __float_as_uint(vap));
                atomicMin(&an2[row], __float_as_uint(van));
            }
        }
    }
}

// ---------- finalize: sqrt + hinge + mean ----------
__global__ __launch_bounds__(256) void finalize_kernel(const unsigned* __restrict__ ap2,
                                                       const unsigned* __restrict__ an2,
                                                       float* __restrict__ out) {
    int tid = threadIdx.x;
    float ls = 0.f, ps = 0.f;
    for (int row = tid; row < N; row += 256) {
        float ap = sqrtf(__uint_as_float(ap2[row]));
        float an = sqrtf(__uint_as_float(an2[row]));
        ls += fmaxf(0.f, MARGIN - (an - ap));
        ps += (an > ap) ? 1.f : 0.f;
    }
    #pragma unroll
    for (int off = 32; off >= 1; off >>= 1) {
        ls += __shfl_xor(ls, off);
        ps += __shfl_xor(ps, off);
    }
    __shared__ float red[2][4];
    int w = tid >> 6;
    if ((tid & 63) == 0) { red[0][w] = ls; red[1][w] = ps; }
    __syncthreads();
    if (tid == 0) {
        float L = red[0][0] + red[0][1] + red[0][2] + red[0][3];
        float P = red[1][0] + red[1][1] + red[1][2] + red[1][3];
        out[0] = L / (float)N;
        out[1] = P / (float)N;
    }
}

extern "C" void kernel_launch(void* const* d_in, const int* in_sizes, int n_in,
                              void* d_out, int out_size, void* d_ws, size_t ws_size,
                              hipStream_t stream) {
    const float* X = (const float*)d_in[0];
    const int* lbl = (const int*)d_in[1];
    float* out = (float*)d_out;

    float* sq = (float*)d_ws;                               // N floats
    unsigned* ap2 = (unsigned*)d_ws + N;                    // N uints
    unsigned* an2 = (unsigned*)d_ws + 2 * N;                // N uints
    unsigned short* Xb = (unsigned short*)((char*)d_ws + 3 * N * sizeof(unsigned)); // N*D bf16

    hipMemsetAsync(ap2, 0x00, N * sizeof(unsigned), stream);   // 0.0f
    hipMemsetAsync(an2, 0x7F, N * sizeof(unsigned), stream);   // ~3.39e38

    convert_kernel<<<N / 16, 256, 0, stream>>>(X, Xb, sq);
    dim3 grid(N / TI, JCH);
    triplet_main<<<grid, 256, 0, stream>>>(Xb, lbl, sq, ap2, an2);
    finalize_kernel<<<1, 256, 0, stream>>>(ap2, an2, out);
}

// Round 3
// 94.506 us; speedup vs baseline: 4.2593x; 1.1316x over previous
//
#include <hip/hip_runtime.h>
#include <hip/hip_bf16.h>
#include <math.h>

#define N 8192
#define D 128
#define MARGIN 0.3f

#define TI 128
#define TJ 128
#define JCH 8
#define JT_PER (N / (TJ * JCH))   // 8 j-tiles per block

typedef float f32x4 __attribute__((ext_vector_type(4)));
typedef short bf16x8 __attribute__((ext_vector_type(8)));
typedef unsigned short u16x8 __attribute__((ext_vector_type(8)));

#define AS1 __attribute__((address_space(1)))
#define AS3 __attribute__((address_space(3)))

__device__ inline void gload_lds16(const void* g, void* l) {
    __builtin_amdgcn_global_load_lds((AS1 void*)(void*)(g), (AS3 void*)(l), 16, 0, 0);
}

__device__ inline unsigned short f2bf(float f) {
    unsigned u = __float_as_uint(f);
    unsigned r = (u + 0x7FFFu + ((u >> 16) & 1u)) >> 16;
    return (unsigned short)r;
}

// ---------- convert fp32 -> bf16 + row norms + init mining arrays ----------
__global__ __launch_bounds__(256) void convert_kernel(const float* __restrict__ X,
                                                      unsigned short* __restrict__ Xb,
                                                      float* __restrict__ sq,
                                                      unsigned* __restrict__ ap2,
                                                      unsigned* __restrict__ an2) {
    int tid = threadIdx.x;
    int row = blockIdx.x * 16 + (tid >> 4);
    int l = tid & 15;
    const float4* p = reinterpret_cast<const float4*>(X + (size_t)row * D + l * 8);
    float4 u = p[0];
    float4 v = p[1];
    float s = u.x*u.x + u.y*u.y + u.z*u.z + u.w*u.w
            + v.x*v.x + v.y*v.y + v.z*v.z + v.w*v.w;
    u16x8 o;
    o[0] = f2bf(u.x); o[1] = f2bf(u.y); o[2] = f2bf(u.z); o[3] = f2bf(u.w);
    o[4] = f2bf(v.x); o[5] = f2bf(v.y); o[6] = f2bf(v.z); o[7] = f2bf(v.w);
    *reinterpret_cast<u16x8*>(Xb + (size_t)row * D + l * 8) = o;
    #pragma unroll
    for (int off = 8; off >= 1; off >>= 1) s += __shfl_xor(s, off);
    if (l == 0) {
        sq[row] = s;
        ap2[row] = 0u;            // 0.0f  (< any clipped d2)
        an2[row] = 0x7F7F7F7Fu;   // huge  (> any d2)
    }
}

// ---------- main: bf16 MFMA Gram tile, A-frags register-resident, B dbuf ----------
// LDS tiles row-major, 16 chunks of 16B per row; LDS chunk c of row r holds
// GLOBAL chunk c ^ (r&7) (swizzle via permuted global source per lane, since
// global_load_lds dest is fixed wave-base + lane*16).
__global__ __launch_bounds__(256, 2) void triplet_main(
        const unsigned short* __restrict__ Xb,
        const int* __restrict__ lbl,
        const float* __restrict__ sq,
        unsigned* __restrict__ ap2,
        unsigned* __restrict__ an2) {
    __shared__ unsigned short BufA[TI * D];   // 32 KB: A staging, then B buf 1
    __shared__ unsigned short BufB[TJ * D];   // 32 KB: B buf 0
    __shared__ float sqj_s[2][TJ];
    __shared__ int   lblj_s[2][TJ];

    const int tid = threadIdx.x;
    const int w = tid >> 6;        // wave 0..3
    const int lane = tid & 63;
    const int wr = w >> 1;         // 2x2 wave grid over 128x128 C
    const int wc = w & 1;
    const int quad = lane >> 4;
    const int lx = lane & 15;
    const int i0 = blockIdx.x * TI;
    const int jbase = blockIdx.y * JT_PER * TJ;

    int lbl_i[16];
    #pragma unroll
    for (int t = 0; t < 4; ++t)
        #pragma unroll
        for (int v = 0; v < 4; ++v)
            lbl_i[t * 4 + v] = lbl[i0 + wr * 64 + t * 16 + quad * 4 + v];

    float m_ap[16], m_an[16];
    #pragma unroll
    for (int q = 0; q < 16; ++q) { m_ap[q] = -INFINITY; m_an[q] = INFINITY; }

    // stage A tile and B tile 0
    #pragma unroll
    for (int t = 0; t < 8; ++t) {
        int rbase = w * 32 + t * 4;
        int r = rbase + quad;
        int gc = lx ^ (r & 7);
        gload_lds16(Xb + (size_t)(i0 + r) * D + gc * 8, &BufA[rbase * D]);
    }
    #pragma unroll
    for (int t = 0; t < 8; ++t) {
        int rbase = w * 32 + t * 4;
        int r = rbase + quad;
        int gc = lx ^ (r & 7);
        gload_lds16(Xb + (size_t)(jbase + r) * D + gc * 8, &BufB[rbase * D]);
    }
    if (tid < TJ) { sqj_s[0][tid] = sq[jbase + tid]; lblj_s[0][tid] = lbl[jbase + tid]; }
    __syncthreads();   // staging visible

    // A fragments -> registers, held across all j-tiles
    bf16x8 af[4][4];
    #pragma unroll
    for (int ks = 0; ks < 4; ++ks)
        #pragma unroll
        for (int t = 0; t < 4; ++t) {
            int rA = wr * 64 + t * 16 + lx;
            int sc = (ks * 4 + quad) ^ (lx & 7);
            af[ks][t] = *reinterpret_cast<const bf16x8*>(&BufA[rA * D + sc * 8]);
        }
    __syncthreads();   // all waves done reading BufA before it becomes B buf 1

    #pragma unroll 1
    for (int jt = 0; jt < JT_PER; ++jt) {
        const int cb = jt & 1;
        const unsigned short* cur = cb ? BufA : BufB;
        unsigned short* nxt = cb ? BufB : BufA;

        // prefetch next B tile into the other buffer (lands during compute)
        if (jt + 1 < JT_PER) {
            const int jb1 = jbase + (jt + 1) * TJ;
            #pragma unroll
            for (int t = 0; t < 8; ++t) {
                int rbase = w * 32 + t * 4;
                int r = rbase + quad;
                int gc = lx ^ (r & 7);
                gload_lds16(Xb + (size_t)(jb1 + r) * D + gc * 8, &nxt[rbase * D]);
            }
            if (tid < TJ) {
                sqj_s[1 - cb][tid] = sq[jb1 + tid];
                lblj_s[1 - cb][tid] = lbl[jb1 + tid];
            }
        }

        f32x4 acc[4][4];
        #pragma unroll
        for (int a = 0; a < 4; ++a)
            #pragma unroll
            for (int b = 0; b < 4; ++b)
                acc[a][b] = (f32x4){0.f, 0.f, 0.f, 0.f};

        #pragma unroll
        for (int ks = 0; ks < 4; ++ks) {
            bf16x8 bf[4];
            #pragma unroll
            for (int t = 0; t < 4; ++t) {
                int rB = wc * 64 + t * 16 + lx;
                int sc = (ks * 4 + quad) ^ (lx & 7);
                bf[t] = *reinterpret_cast<const bf16x8*>(&cur[rB * D + sc * 8]);
            }
            #pragma unroll
            for (int tr = 0; tr < 4; ++tr)
                #pragma unroll
                for (int tc = 0; tc < 4; ++tc)
                    acc[tr][tc] = __builtin_amdgcn_mfma_f32_16x16x32_bf16(
                        af[ks][tr], bf[tc], acc[tr][tc], 0, 0, 0);
        }

        // epilogue: masked running max/min on v = sq_j - 2*dot
        #pragma unroll
        for (int tc = 0; tc < 4; ++tc) {
            int cj = wc * 64 + tc * 16 + lx;
            int ljv = lblj_s[cb][cj];
            float sjv = sqj_s[cb][cj];
            #pragma unroll
            for (int tr = 0; tr < 4; ++tr) {
                #pragma unroll
                for (int v = 0; v < 4; ++v) {
                    float val = fmaf(-2.f, acc[tr][tc][v], sjv);
                    bool same = (ljv == lbl_i[tr * 4 + v]);
                    int q = tr * 4 + v;
                    m_ap[q] = same ? fmaxf(m_ap[q], val) : m_ap[q];
                    m_an[q] = same ? m_an[q] : fminf(m_an[q], val);
                }
            }
        }
        __syncthreads();   // readers of cur done; staging into nxt drained
    }

    // reduce over the 16 j-stripe lanes of each quad, then one atomic pair/row
    #pragma unroll
    for (int off = 8; off >= 1; off >>= 1) {
        #pragma unroll
        for (int q = 0; q < 16; ++q) {
            m_ap[q] = fmaxf(m_ap[q], __shfl_xor(m_ap[q], off));
            m_an[q] = fminf(m_an[q], __shfl_xor(m_an[q], off));
        }
    }
    if (lx == 0) {
        #pragma unroll
        for (int t = 0; t < 4; ++t) {
            #pragma unroll
            for (int v = 0; v < 4; ++v) {
                int row = i0 + wr * 64 + t * 16 + quad * 4 + v;
                float si = sq[row];
                float vap = fmaxf(si + m_ap[t * 4 + v], 1e-12f);
                float van = fmaxf(si + m_an[t * 4 + v], 1e-12f);
                atomicMax(&ap2[row], __float_as_uint(vap));
                atomicMin(&an2[row], __float_as_uint(van));
            }
        }
    }
}

// ---------- finalize: sqrt + hinge + mean ----------
__global__ __launch_bounds__(1024) void finalize_kernel(const unsigned* __restrict__ ap2,
                                                        const unsigned* __restrict__ an2,
                                                        float* __restrict__ out) {
    int tid = threadIdx.x;
    float ls = 0.f, ps = 0.f;
    for (int row = tid; row < N; row += 1024) {
        float ap = sqrtf(__uint_as_float(ap2[row]));
        float an = sqrtf(__uint_as_float(an2[row]));
        ls += fmaxf(0.f, MARGIN - (an - ap));
        ps += (an > ap) ? 1.f : 0.f;
    }
    #pragma unroll
    for (int off = 32; off >= 1; off >>= 1) {
        ls += __shfl_xor(ls, off);
        ps += __shfl_xor(ps, off);
    }
    __shared__ float red[2][16];
    int w = tid >> 6;
    if ((tid & 63) == 0) { red[0][w] = ls; red[1][w] = ps; }
    __syncthreads();
    if (tid == 0) {
        float L = 0.f, P = 0.f;
        #pragma unroll
        for (int i = 0; i < 16; ++i) { L += red[0][i]; P += red[1][i]; }
        out[0] = L / (float)N;
        out[1] = P / (float)N;
    }
}

extern "C" void kernel_launch(void* const* d_in, const int* in_sizes, int n_in,
                              void* d_out, int out_size, void* d_ws, size_t ws_size,
                              hipStream_t stream) {
    const float* X = (const float*)d_in[0];
    const int* lbl = (const int*)d_in[1];
    float* out = (float*)d_out;

    float* sq = (float*)d_ws;                               // N floats
    unsigned* ap2 = (unsigned*)d_ws + N;                    // N uints
    unsigned* an2 = (unsigned*)d_ws + 2 * N;                // N uints
    unsigned short* Xb = (unsigned short*)((char*)d_ws + 3 * N * sizeof(unsigned)); // N*D bf16

    convert_kernel<<<N / 16, 256, 0, stream>>>(X, Xb, sq, ap2, an2);
    dim3 grid(N / TI, JCH);
    triplet_main<<<grid, 256, 0, stream>>>(Xb, lbl, sq, ap2, an2);
    finalize_kernel<<<1, 1024, 0, stream>>>(ap2, an2, out);
}